// Round 1
// baseline (701.973 us; speedup 1.0000x reference)
//
#include <hip/hip_runtime.h>
#include <stdint.h>

typedef __bf16 bf16x8 __attribute__((ext_vector_type(8)));
typedef float f32x4 __attribute__((ext_vector_type(4)));
typedef float f32x2 __attribute__((ext_vector_type(2)));

#define DEV __device__ __forceinline__

constexpr int NB = 8, NT = 96, DEP = 300, DM = 768, NH = 12;
constexpr int KP = 320;                  // padded K for the projection GEMM
constexpr int MROWS = NB * NT * NT;      // 73728
constexpr int NOUT = 3 * DM;             // 2304  (q | k | v)

DEV ushort f2bf(float f) {
  union { float f; uint32_t u; } v; v.f = f;
  uint32_t r = v.u + 0x7FFFu + ((v.u >> 16) & 1u);
  return (ushort)(r >> 16);
}
DEV float bf2f(ushort h) {
  union { uint32_t u; float f; } v; v.u = ((uint32_t)h) << 16;
  return v.f;
}

// ---------- kernel 1: edge fp32 -> bf16, K padded 300->320 with zeros ----------
__global__ void k_convert_x(const float* __restrict__ edge, ushort* __restrict__ Xb) {
  const int total = MROWS * (KP / 8);
  for (int t = blockIdx.x * blockDim.x + threadIdx.x; t < total;
       t += gridDim.x * blockDim.x) {
    int row = t / (KP / 8);
    int g = t - row * (KP / 8);
    int c0 = g * 8;
    alignas(16) ushort o[8];
    if (c0 + 8 <= DEP) {
      const float* src = edge + (int64_t)row * DEP + c0;
      f32x4 a = *reinterpret_cast<const f32x4*>(src);
      f32x4 b = *reinterpret_cast<const f32x4*>(src + 4);
#pragma unroll
      for (int u = 0; u < 4; ++u) { o[u] = f2bf(a[u]); o[4 + u] = f2bf(b[u]); }
    } else {
#pragma unroll
      for (int u = 0; u < 8; ++u) {
        int c = c0 + u;
        o[u] = (c < DEP) ? f2bf(edge[(int64_t)row * DEP + c]) : (ushort)0;
      }
    }
    *reinterpret_cast<bf16x8*>(Xb + (int64_t)row * KP + c0) =
        *reinterpret_cast<const bf16x8*>(o);
  }
}

// ---------- kernel 2: W^T (bf16, K-padded) + fused bias vector ----------
__global__ void k_convert_w(const float* __restrict__ Wq, const float* __restrict__ bq,
                            const float* __restrict__ Wk, const float* __restrict__ bk,
                            const float* __restrict__ Wv, const float* __restrict__ bv,
                            ushort* __restrict__ Wbt, float* __restrict__ biasv) {
  int t = blockIdx.x * blockDim.x + threadIdx.x;
  const int total = NOUT * KP;
  if (t < total) {
    int c = t / KP, k = t - (t / KP) * KP;
    int which = c / DM, cc = c % DM;
    const float* W = which == 0 ? Wq : (which == 1 ? Wk : Wv);
    float v = (k < DEP) ? W[k * DM + cc] : 0.f;
    Wbt[t] = f2bf(v);
  }
  if (t < NOUT) {
    int which = t / DM, cc = t % DM;
    const float* bb = which == 0 ? bq : (which == 1 ? bk : bv);
    biasv[t] = bb[cc];
  }
}

// ---------- kernel 3: QKV projection GEMM (bf16 MFMA 16x16x32) ----------
// C[73728][2304] = Xb[73728][320] * Wbt^T + bias ; Wbt stored [outcol][k]
__launch_bounds__(256, 2)
__global__ void k_gemm(const ushort* __restrict__ Xb, const ushort* __restrict__ Wbt,
                       const float* __restrict__ biasv, ushort* __restrict__ QKV) {
  constexpr int BM = 128, BN = 128, BK = 64, LS = 72;  // +8 pad: 2-way-free LDS reads
  __shared__ ushort As[BM * LS];
  __shared__ ushort Bs[BN * LS];
  const int bn = blockIdx.x % (NOUT / BN);
  const int bm = blockIdx.x / (NOUT / BN);
  const int tid = threadIdx.x;
  const int wid = tid >> 6, lane = tid & 63;
  const int wr = wid >> 1, wc = wid & 1;
  const int l15 = lane & 15, lq = lane >> 4;
  f32x4 acc[4][4] = {};
  const int64_t arow0 = (int64_t)bm * BM;
  const int64_t brow0 = (int64_t)bn * BN;

  for (int kt = 0; kt < KP / BK; ++kt) {
#pragma unroll
    for (int p = 0; p < 4; ++p) {
      int task = p * 256 + tid;            // 1024 tasks: 128 rows x 8 segs
      int row = task >> 3, seg = task & 7;
      bf16x8 av = *reinterpret_cast<const bf16x8*>(Xb + (arow0 + row) * KP + kt * BK + seg * 8);
      *reinterpret_cast<bf16x8*>(As + row * LS + seg * 8) = av;
      bf16x8 bv = *reinterpret_cast<const bf16x8*>(Wbt + (brow0 + row) * KP + kt * BK + seg * 8);
      *reinterpret_cast<bf16x8*>(Bs + row * LS + seg * 8) = bv;
    }
    __syncthreads();
#pragma unroll
    for (int kk = 0; kk < 2; ++kk) {
      bf16x8 af[4], bfr[4];
#pragma unroll
      for (int mf = 0; mf < 4; ++mf)
        af[mf] = *reinterpret_cast<const bf16x8*>(As + (wr * 64 + mf * 16 + l15) * LS + kk * 32 + lq * 8);
#pragma unroll
      for (int nf = 0; nf < 4; ++nf)
        bfr[nf] = *reinterpret_cast<const bf16x8*>(Bs + (wc * 64 + nf * 16 + l15) * LS + kk * 32 + lq * 8);
#pragma unroll
      for (int mf = 0; mf < 4; ++mf)
#pragma unroll
        for (int nf = 0; nf < 4; ++nf)
          acc[mf][nf] = __builtin_amdgcn_mfma_f32_16x16x32_bf16(af[mf], bfr[nf], acc[mf][nf], 0, 0, 0);
    }
    __syncthreads();
  }
#pragma unroll
  for (int nf = 0; nf < 4; ++nf) {
    int col = bn * BN + wc * 64 + nf * 16 + l15;
    float bias = biasv[col];
#pragma unroll
    for (int mf = 0; mf < 4; ++mf)
#pragma unroll
      for (int r = 0; r < 4; ++r) {
        int row = bm * BM + wr * 64 + mf * 16 + lq * 4 + r;
        QKV[(int64_t)row * NOUT + col] = f2bf(acc[mf][nf][r] + bias);
      }
  }
}

// ---------- kernel 4: per-(b,n,h) attention ----------
// block = 256 thr = 4 waves = 2 heads x 2 i-halves. V^T staged to LDS with
// mod-96 row shift (bank-conflict-free b128 reads); P staged with +8 pad.
__launch_bounds__(256, 2)
__global__ void k_attn(const ushort* __restrict__ QKV, const int* __restrict__ masks,
                       ushort* __restrict__ merged) {
  __shared__ ushort Vt[2][64 * 96];      // [head][d][j'], j' = (j + 8*(d&7)) % 96
  __shared__ ushort Pl[4][48 * 104];     // per-wave P, stride 104
  const int blk = blockIdx.x;
  const int hp = blk % (NH / 2);
  const int n = (blk / (NH / 2)) % NT;
  const int b = blk / ((NH / 2) * NT);
  const int tid = threadIdx.x, wid = tid >> 6, lane = tid & 63;
  const int hloc = wid >> 1, ihalf = wid & 1;
  const int h = hp * 2 + hloc;
  const int l15 = lane & 15, lq = lane >> 4;
  const int row0 = (b * NT + n) * NT;

  // stage V^T for the block's two heads (coalesced 16B global reads)
  for (int t = tid; t < 2 * 96 * 8; t += 256) {
    int dg = t & 7;
    int j = (t >> 3) % 96;
    int hh = t / 768;
    bf16x8 v = *reinterpret_cast<const bf16x8*>(
        QKV + (int64_t)(row0 + j) * NOUT + 2 * DM + (hp * 2 + hh) * 64 + dg * 8);
#pragma unroll
    for (int u = 0; u < 8; ++u) {
      int d = dg * 8 + u;
      int js = j + 8 * (d & 7); if (js >= 96) js -= 96;
      Vt[hh][d * 96 + js] = ((const ushort*)&v)[u];
    }
  }

  // persistent K fragments (B-operand of QK^T), read once from global
  bf16x8 kb[6][2];
#pragma unroll
  for (int nf = 0; nf < 6; ++nf)
#pragma unroll
    for (int kk = 0; kk < 2; ++kk)
      kb[nf][kk] = *reinterpret_cast<const bf16x8*>(
          QKV + (int64_t)(row0 + nf * 16 + l15) * NOUT + DM + h * 64 + kk * 32 + lq * 8);

  __syncthreads();

  const int i0 = ihalf * 48;
  // ---- scores = Q K^T (48 x 96) ----
  f32x4 sc[3][6] = {};
#pragma unroll
  for (int mf = 0; mf < 3; ++mf) {
    bf16x8 af[2];
#pragma unroll
    for (int kk = 0; kk < 2; ++kk)
      af[kk] = *reinterpret_cast<const bf16x8*>(
          QKV + (int64_t)(row0 + i0 + mf * 16 + l15) * NOUT + h * 64 + kk * 32 + lq * 8);
#pragma unroll
    for (int kk = 0; kk < 2; ++kk)
#pragma unroll
      for (int nf = 0; nf < 6; ++nf)
        sc[mf][nf] = __builtin_amdgcn_mfma_f32_16x16x32_bf16(af[kk], kb[nf][kk], sc[mf][nf], 0, 0, 0);
  }

  // ---- masked softmax over j, fold 1/(8*rowsum) ----
#pragma unroll
  for (int mf = 0; mf < 3; ++mf) {
#pragma unroll
    for (int r = 0; r < 4; ++r) {
      int iloc = i0 + mf * 16 + lq * 4 + r;
      int mk = masks[row0 + iloc];       // uniform across the 16-lane group
      if (mk == 0) {
#pragma unroll
        for (int nf = 0; nf < 6; ++nf) sc[mf][nf][r] = 0.f;  // -> exact uniform softmax
      }
      float mx = sc[mf][0][r];
#pragma unroll
      for (int nf = 1; nf < 6; ++nf) mx = fmaxf(mx, sc[mf][nf][r]);
      mx = fmaxf(mx, __shfl_xor(mx, 1));
      mx = fmaxf(mx, __shfl_xor(mx, 2));
      mx = fmaxf(mx, __shfl_xor(mx, 4));
      mx = fmaxf(mx, __shfl_xor(mx, 8));
      float sum = 0.f;
#pragma unroll
      for (int nf = 0; nf < 6; ++nf) {
        float e = __expf(sc[mf][nf][r] - mx);
        sc[mf][nf][r] = e;
        sum += e;
      }
      sum += __shfl_xor(sum, 1);
      sum += __shfl_xor(sum, 2);
      sum += __shfl_xor(sum, 4);
      sum += __shfl_xor(sum, 8);
      float inv = 1.f / (8.f * sum);     // / sqrt(HD) folded here
#pragma unroll
      for (int nf = 0; nf < 6; ++nf) sc[mf][nf][r] *= inv;
    }
  }

  // ---- write P (bf16) to LDS ----
  ushort* Pw = &Pl[wid][0];
#pragma unroll
  for (int mf = 0; mf < 3; ++mf)
#pragma unroll
    for (int nf = 0; nf < 6; ++nf)
#pragma unroll
      for (int r = 0; r < 4; ++r)
        Pw[(mf * 16 + lq * 4 + r) * 104 + nf * 16 + l15] = f2bf(sc[mf][nf][r]);

  // ---- merged = P V (48 x 64) ----
  f32x4 oacc[3][4] = {};
#pragma unroll
  for (int kt = 0; kt < 3; ++kt) {
    bf16x8 pa[3], vb[4];
#pragma unroll
    for (int mf = 0; mf < 3; ++mf)
      pa[mf] = *reinterpret_cast<const bf16x8*>(&Pw[(mf * 16 + l15) * 104 + kt * 32 + lq * 8]);
#pragma unroll
    for (int nf = 0; nf < 4; ++nf) {
      int d = nf * 16 + l15;
      int js = kt * 32 + lq * 8 + 8 * (d & 7); if (js >= 96) js -= 96;
      vb[nf] = *reinterpret_cast<const bf16x8*>(&Vt[hloc][d * 96 + js]);
    }
#pragma unroll
    for (int mf = 0; mf < 3; ++mf)
#pragma unroll
      for (int nf = 0; nf < 4; ++nf)
        oacc[mf][nf] = __builtin_amdgcn_mfma_f32_16x16x32_bf16(pa[mf], vb[nf], oacc[mf][nf], 0, 0, 0);
  }

#pragma unroll
  for (int mf = 0; mf < 3; ++mf)
#pragma unroll
    for (int nf = 0; nf < 4; ++nf)
#pragma unroll
      for (int r = 0; r < 4; ++r) {
        int iloc = i0 + mf * 16 + lq * 4 + r;
        int col = h * 64 + nf * 16 + l15;
        merged[(int64_t)(row0 + iloc) * DM + col] = f2bf(oacc[mf][nf][r]);
      }
}

// ---------- kernel 5: pairwise alpha-blend combine ----------
// one wave per unordered pair {i,j}; produces out[b,i,j,:] and out[b,j,i,:]
__launch_bounds__(256)
__global__ void k_combine(const ushort* __restrict__ merged, const float* __restrict__ Wa,
                          const float* __restrict__ ba, float* __restrict__ out) {
  const int wid = threadIdx.x >> 6, lane = threadIdx.x & 63;
  const int TPB = NT * 49;  // 4704 wave-tasks per batch (jj in [0,48])
  int64_t task = (int64_t)blockIdx.x * 4 + wid;
  if (task >= (int64_t)NB * TPB) return;
  int b = (int)(task / TPB);
  int rem = (int)(task % TPB);
  int i = rem / 49, jj = rem % 49;
  if (jj == 48 && i >= 48) return;  // cyclic-distance-48 pairs counted once
  int j = (i + jj) % NT;

  const ushort* mij = merged + ((int64_t)(b * NT + i) * NT + j) * DM;
  const ushort* mji = merged + ((int64_t)(b * NT + j) * NT + i) * DM;
  uint dij[6], dji[6];
  f32x2 wlo[6], whi[6];
#pragma unroll
  for (int q = 0; q < 6; ++q) {
    int e2 = lane + q * 64;
    dij[q] = reinterpret_cast<const uint*>(mij)[e2];
    dji[q] = reinterpret_cast<const uint*>(mji)[e2];
    wlo[q] = reinterpret_cast<const f32x2*>(Wa)[e2];
    whi[q] = reinterpret_cast<const f32x2*>(Wa + DM)[e2];
  }
  float s1 = 0, s2 = 0, s3 = 0, s4 = 0;
#pragma unroll
  for (int q = 0; q < 6; ++q) {
    float a0 = bf2f((ushort)(dij[q] & 0xffff)), a1 = bf2f((ushort)(dij[q] >> 16));
    float b0 = bf2f((ushort)(dji[q] & 0xffff)), b1 = bf2f((ushort)(dji[q] >> 16));
    s1 += a0 * wlo[q][0] + a1 * wlo[q][1];
    s2 += a0 * whi[q][0] + a1 * whi[q][1];
    s3 += b0 * wlo[q][0] + b1 * wlo[q][1];
    s4 += b0 * whi[q][0] + b1 * whi[q][1];
  }
#pragma unroll
  for (int d = 1; d < 64; d <<= 1) {
    s1 += __shfl_xor(s1, d);
    s2 += __shfl_xor(s2, d);
    s3 += __shfl_xor(s3, d);
    s4 += __shfl_xor(s4, d);
  }
  float bav = ba[0];
  float aij = 1.f / (1.f + __expf(-(s1 + s4 + bav)));
  float aji = 1.f / (1.f + __expf(-(s3 + s2 + bav)));
  float* oij = out + ((int64_t)(b * NT + i) * NT + j) * DM;
  float* oji = out + ((int64_t)(b * NT + j) * NT + i) * DM;
#pragma unroll
  for (int q = 0; q < 6; ++q) {
    int e2 = lane + q * 64;
    float a0 = bf2f((ushort)(dij[q] & 0xffff)), a1 = bf2f((ushort)(dij[q] >> 16));
    float b0 = bf2f((ushort)(dji[q] & 0xffff)), b1 = bf2f((ushort)(dji[q] >> 16));
    f32x2 r0, r1;
    r0[0] = a0 + aij * (b0 - a0); r0[1] = a1 + aij * (b1 - a1);
    r1[0] = b0 + aji * (a0 - b0); r1[1] = b1 + aji * (a1 - b1);
    reinterpret_cast<f32x2*>(oij)[e2] = r0;
    reinterpret_cast<f32x2*>(oji)[e2] = r1;
  }
}

extern "C" void kernel_launch(void* const* d_in, const int* in_sizes, int n_in,
                              void* d_out, int out_size, void* d_ws, size_t ws_size,
                              hipStream_t stream) {
  const float* edge = (const float*)d_in[0];
  const int* masks = (const int*)d_in[1];
  const float* Wq = (const float*)d_in[2];
  const float* bq = (const float*)d_in[3];
  const float* Wk = (const float*)d_in[4];
  const float* bk = (const float*)d_in[5];
  const float* Wv = (const float*)d_in[6];
  const float* bv = (const float*)d_in[7];
  const float* Wa = (const float*)d_in[8];
  const float* ba = (const float*)d_in[9];
  float* out = (float*)d_out;

  char* ws = (char*)d_ws;
  // Xb (47 MB) and merged (113 MB) share [0, ...): Xb is dead before attn runs.
  ushort* Xb = (ushort*)ws;
  ushort* merged = (ushort*)ws;
  ushort* Wbt = (ushort*)(ws + 113246208);
  float* biasv = (float*)(ws + 114720768);
  ushort* QKV = (ushort*)(ws + 114729984);
  // total: 454,468,608 bytes

  k_convert_x<<<2048, 256, 0, stream>>>(edge, Xb);
  k_convert_w<<<(NOUT * KP + 255) / 256, 256, 0, stream>>>(Wq, bq, Wk, bk, Wv, bv, Wbt, biasv);
  k_gemm<<<(MROWS / 128) * (NOUT / 128), 256, 0, stream>>>(Xb, Wbt, biasv, QKV);
  k_attn<<<NB * NT * (NH / 2), 256, 0, stream>>>(QKV, masks, merged);
  k_combine<<<(NB * NT * 49) / 4, 256, 0, stream>>>(merged, Wa, ba, out);
}